// Round 8
// baseline (120.726 us; speedup 1.0000x reference)
//
#include <hip/hip_runtime.h>

#define B 4096
#define S 200
#define EMB_DIM 128
#define HIDDEN 256
#define NUM_CLASSES 20
#define VOCAB 100000

// ---------------------------------------------------------------------------
// Pass 1 (unchanged since R5, ~10.2 us): fp32 table -> int8 with per-row
// scale. 51.2 MB read + 13.2 MB written, streamed. Row 0 stays all zero
// (scale 0) so padding reads are exact.
// ---------------------------------------------------------------------------
__global__ __launch_bounds__(256) void convert_q8(
    const float* __restrict__ emb,          // [VOCAB*EMB_DIM]
    signed char* __restrict__ qt,           // [VOCAB*EMB_DIM] int8
    float* __restrict__ scl)                // [VOCAB] per-row scale
{
    const int  t    = threadIdx.x;
    const long base = (long)blockIdx.x * 1024 + t * 4;   // element index
    const float4 v  = *(const float4*)(emb + base);

    float m = fmaxf(fmaxf(fabsf(v.x), fabsf(v.y)),
                    fmaxf(fabsf(v.z), fabsf(v.w)));
    #pragma unroll
    for (int off = 1; off < 32; off <<= 1)               // 32-lane row group
        m = fmaxf(m, __shfl_xor(m, off, 64));

    const float inv = m > 0.f ? 127.f / m : 0.f;
    const int q0 = __float2int_rn(v.x * inv);
    const int q1 = __float2int_rn(v.y * inv);
    const int q2 = __float2int_rn(v.z * inv);
    const int q3 = __float2int_rn(v.w * inv);
    const unsigned pk = (q0 & 255) | ((q1 & 255) << 8)
                      | ((q2 & 255) << 16) | ((q3 & 255) << 24);
    *(unsigned*)(qt + base) = pk;

    if ((t & 31) == 0) scl[base >> 7] = m * (1.f / 127.f);
}

// ---------------------------------------------------------------------------
// Pass 2: fused gather + mean-pool + MLP. R7 (wave-independent gather) won
// -2.6 us and Little's law says wave concurrency no longer binds (32 waves/CU
// x 2 KB in flight >> needed). The remaining computable serial term is W1:
// 2048 blocks x 131 KB = 268 MB of L2 streaming (~7.8 us/CU). This version
// keeps R7's per-wave gather EXACTLY (2 waves/sample, depth-2 pipeline,
// 8-row uint4 loads, shfl_xor reduce) but packs 4 samples into 512-thread
// blocks: grid 1024, 4 blocks/CU x 8 waves = 32 waves/CU (same occupancy),
// W1 traffic halved to ~134 MB. Pre-committed: if null, fused ~26.5 us is
// the random-gather service floor -> ROOFLINE next round.
// ---------------------------------------------------------------------------
__global__ __launch_bounds__(512, 8) void fused_kernel(
    const int* __restrict__ x,              // [B, S]
    const int* __restrict__ lens,           // [B]
    const signed char* __restrict__ qt,     // [VOCAB, EMB_DIM] int8
    const float* __restrict__ scl,          // [VOCAB]
    const float* __restrict__ W1,           // [EMB_DIM, HIDDEN]
    const float* __restrict__ b1,           // [HIDDEN]
    const float* __restrict__ W2,           // [HIDDEN, NUM_CLASSES]
    const float* __restrict__ b2,           // [NUM_CLASSES]
    float* __restrict__ out)                // [B, NUM_CLASSES]
{
    __shared__ int   sidx[4][256];               // 4 KB
    __shared__ float Pp[8][EMB_DIM];             // 4 KB per-wave partials
    __shared__ float P[4][EMB_DIM];              // 2 KB
    __shared__ float H[4][HIDDEN];               // 4 KB
    __shared__ float part[4][4][NUM_CLASSES];    // 1.25 KB

    const int t  = threadIdx.x;
    const int b0 = blockIdx.x * 4;

    // Stage indices for 4 samples; zeros beyond L -> row 0 (exact padding).
    #pragma unroll
    for (int r = 0; r < 4; ++r) {
        const int Lr = lens[b0 + r];             // uniform -> s_load, cached
        int v = 0;
        if (t < 256) {
            if (t < Lr) v = x[(long)(b0 + r) * S + t];   // L <= 199 < 256
            sidx[r][t] = v;
        }
    }
    __syncthreads();

    const int l    = t & 63;
    const int wid  = t >> 6;        // wave 0..7
    const int smp  = wid >> 1;      // sample 0..3 (uniform per wave)
    const int w    = wid & 1;       // wave-within-sample 0/1
    const int slot = l >> 3;        // position slot 0..7 within a chunk
    const int sub  = l & 7;         // 16B piece of the 128B int8 row
    const int soff = sub << 4;      // byte offset within the row

    const int Lw  = lens[b0 + smp];                                  // uniform
    const int nCh = __builtin_amdgcn_readfirstlane((Lw + 7) >> 3);   // 1..25

    float acc[16];
    #pragma unroll
    for (int f = 0; f < 16; ++f) acc[f] = 0.f;

    // Depth-2 pipeline over this wave's chunks (w, w+2, w+4, ...).
    // Prefetch bound: max sidx index = (24+2)*8+7 = 215 < 256.
    int   idx0 = sidx[smp][(w << 3) + slot];
    uint4 v0   = *(const uint4*)(qt + (((long)idx0 << 7) + soff));
    float s0   = scl[idx0];

    for (int c = w; c < nCh; c += 2) {
        const int   idxN = sidx[smp][((c + 2) << 3) + slot];
        const uint4 vN   = *(const uint4*)(qt + (((long)idxN << 7) + soff));
        const float sN   = scl[idxN];

        #pragma unroll
        for (int q = 0; q < 4; ++q) {
            const unsigned cc = q == 0 ? v0.x : q == 1 ? v0.y : q == 2 ? v0.z : v0.w;
            acc[q * 4 + 0] = fmaf(s0, (float)((int)(cc << 24) >> 24), acc[q * 4 + 0]);
            acc[q * 4 + 1] = fmaf(s0, (float)((int)(cc << 16) >> 24), acc[q * 4 + 1]);
            acc[q * 4 + 2] = fmaf(s0, (float)((int)(cc <<  8) >> 24), acc[q * 4 + 2]);
            acc[q * 4 + 3] = fmaf(s0, (float)((int)(cc      ) >> 24), acc[q * 4 + 3]);
        }
        v0 = vN; s0 = sN; idx0 = idxN;
    }

    // In-wave reduce across the 8 position slots (lane bits 3,4,5).
    #pragma unroll
    for (int f = 0; f < 16; ++f) {
        acc[f] += __shfl_xor(acc[f],  8, 64);
        acc[f] += __shfl_xor(acc[f], 16, 64);
        acc[f] += __shfl_xor(acc[f], 32, 64);
    }
    if (slot == 0) {                 // lanes 0..7: dims [sub*16, sub*16+16)
        #pragma unroll
        for (int f = 0; f < 16; ++f)
            Pp[wid][(sub << 4) + f] = acc[f];
    }
    __syncthreads();

    // Combine the 2 waves' partials per sample; divide by L.
    {
        const int s2  = t >> 7;                  // sample 0..3
        const int dim = t & 127;
        const float Lf = (float)lens[b0 + s2];   // L2-hot
        P[s2][dim] = (Pp[2 * s2][dim] + Pp[2 * s2 + 1][dim]) / Lf;
    }
    __syncthreads();

    // Layer 1: 512 threads = 2 groups x 256 units; group pr handles samples
    // 2pr, 2pr+1. The two groups stream W1 in phase -> second read L1-hits.
    {
        const int u  = t & 255;
        const int pr = t >> 8;                   // 0/1
        const int sA = 2 * pr, sB = 2 * pr + 1;
        float hAa = 0.f, hAb = 0.f, hBa = 0.f, hBb = 0.f;
        for (int k = 0; k < EMB_DIM; k += 2) {
            const float wa = W1[(k)     * HIDDEN + u];
            const float wb = W1[(k + 1) * HIDDEN + u];
            hAa = fmaf(P[sA][k],     wa, hAa);
            hAb = fmaf(P[sA][k + 1], wb, hAb);
            hBa = fmaf(P[sB][k],     wa, hBa);
            hBb = fmaf(P[sB][k + 1], wb, hBb);
        }
        const float bb = b1[u];
        H[sA][u] = fmaxf(hAa + hAb + bb, 0.f);
        H[sB][u] = fmaxf(hBa + hBb + bb, 0.f);
    }
    __syncthreads();

    // Layer 2: 4 samples x 4 k-segments x 20 classes = 320 threads, 64-FMA.
    if (t < 4 * 4 * NUM_CLASSES) {
        const int r  = t / (4 * NUM_CLASSES);
        const int u  = t - r * 4 * NUM_CLASSES;
        const int j  = u / NUM_CLASSES;
        const int c  = u - j * NUM_CLASSES;
        const int k0 = j * 64;
        float a = 0.f;
        for (int k = k0; k < k0 + 64; ++k)
            a = fmaf(H[r][k], W2[k * NUM_CLASSES + c], a);
        part[r][j][c] = a;
    }
    __syncthreads();

    if (t < 4 * NUM_CLASSES) {
        const int r = t / NUM_CLASSES;
        const int c = t - r * NUM_CLASSES;
        out[(long)(b0 + r) * NUM_CLASSES + c] =
            b2[c] + part[r][0][c] + part[r][1][c]
                  + part[r][2][c] + part[r][3][c];
    }
}

extern "C" void kernel_launch(void* const* d_in, const int* in_sizes, int n_in,
                              void* d_out, int out_size, void* d_ws, size_t ws_size,
                              hipStream_t stream) {
    const int*   x    = (const int*)d_in[0];
    const int*   lens = (const int*)d_in[1];
    const float* emb  = (const float*)d_in[2];
    const float* W1   = (const float*)d_in[3];
    const float* b1   = (const float*)d_in[4];
    const float* W2   = (const float*)d_in[5];
    const float* b2   = (const float*)d_in[6];
    float*       out  = (float*)d_out;

    signed char* qt  = (signed char*)d_ws;                   // 12.8 MB int8 table
    float*       scl = (float*)((char*)d_ws + (16l << 20));  // 400 KB row scales

    convert_q8<<<(VOCAB * EMB_DIM) / (4 * 256), 256, 0, stream>>>(emb, qt, scl);
    fused_kernel<<<B / 4, 512, 0, stream>>>(x, lens, qt, scl, W1, b1, W2, b2, out);
}